// Round 1
// baseline (245.183 us; speedup 1.0000x reference)
//
#include <hip/hip_runtime.h>
#include <cstddef>

// Problem constants (B,W,D,H,C) = (2,16,16,16,32), N = 4096
#define NN 4096
#define CH 32
#define TI 32   // rows per block in kD
#define TJ 64   // j-chunk in kD

// ---------------------------------------------------------------------------
// Kernel A: fused projections.
// Q conv: 3-tap along d (spatial +-16), K: along w (+-256), J: along h (+-1),
// V: 1x1x1. proj = relu((conv + bias)*scale + offset).
// Outputs: Qf/Kf/Jf as flat [b][spatial*8+co] (== the reshaped 8xN view),
//          Vf as [b][spatial*32+co].
// One wave per spatial point: lanes 0-31 -> V, 32-39 Q, 40-47 K, 48-55 J.
// ---------------------------------------------------------------------------
__global__ __launch_bounds__(256) void kA(
    const float* __restrict__ x,
    const float* __restrict__ qw, const float* __restrict__ qb,
    const float* __restrict__ qs, const float* __restrict__ qo,
    const float* __restrict__ kw, const float* __restrict__ kb,
    const float* __restrict__ ks, const float* __restrict__ ko,
    const float* __restrict__ jw, const float* __restrict__ jb,
    const float* __restrict__ js, const float* __restrict__ jo,
    const float* __restrict__ vw, const float* __restrict__ vb,
    const float* __restrict__ vs, const float* __restrict__ vo,
    float* __restrict__ Qf, float* __restrict__ Kf,
    float* __restrict__ Jf, float* __restrict__ Vf)
{
    const int t    = threadIdx.x;
    const int gsp  = blockIdx.x * 4 + (t >> 6);   // global spatial point id
    const int lane = t & 63;
    const int b    = gsp >> 12;
    const int sp   = gsp & 4095;
    const int w = sp >> 8, d = (sp >> 4) & 15, h = sp & 15;
    const float* xb = x + (size_t)b * 131072;

    if (lane < 32) {
        // V: pointwise 32->32
        const int co = lane;
        const float* xp = xb + (size_t)sp * 32;
        float a = 0.f;
        #pragma unroll 8
        for (int ci = 0; ci < 32; ++ci) a += xp[ci] * vw[ci * 32 + co];
        a = (a + vb[co]) * vs[co] + vo[co];
        Vf[(size_t)b * 131072 + (size_t)sp * 32 + co] = fmaxf(a, 0.f);
    } else {
        const int grp = (lane - 32) >> 3;   // 0=Q,1=K,2=J
        const int co  = lane & 7;
        if (grp < 3) {
            const float* wgt   = (grp == 0) ? qw : (grp == 1) ? kw : jw;
            const int   coord  = (grp == 0) ? d  : (grp == 1) ? w  : h;
            const int   stride = (grp == 0) ? 16 : (grp == 1) ? 256 : 1;
            float a = 0.f;
            #pragma unroll
            for (int dt = 0; dt < 3; ++dt) {
                const int cc = coord + dt - 1;
                if (cc < 0 || cc > 15) continue;   // SAME zero-pad
                const float* xp = xb + (size_t)(sp + (dt - 1) * stride) * 32;
                const float* wp = wgt + dt * 256 + co;   // [t][ci][co] flat: t*256+ci*8+co
                #pragma unroll 8
                for (int ci = 0; ci < 32; ++ci) a += xp[ci] * wp[ci * 8];
            }
            const float* bb = (grp == 0) ? qb : (grp == 1) ? kb : jb;
            const float* ss = (grp == 0) ? qs : (grp == 1) ? ks : js;
            const float* oo = (grp == 0) ? qo : (grp == 1) ? ko : jo;
            a = (a + bb[co]) * ss[co] + oo[co];
            float* dst = (grp == 0) ? Qf : (grp == 1) ? Kf : Jf;
            dst[(size_t)b * 32768 + (size_t)sp * 8 + co] = fmaxf(a, 0.f);
        }
    }
}

// ---------------------------------------------------------------------------
// Kernel B: M[b][r][s] = dot(K_row_r, J_row_s) over N=4096.
// One block per (b,r,s) pair: 128 blocks x 256 threads, block reduction.
// ---------------------------------------------------------------------------
__global__ __launch_bounds__(256) void kB(
    const float* __restrict__ Kf, const float* __restrict__ Jf,
    float* __restrict__ M)
{
    const int pair = blockIdx.x;           // b*64 + r*8 + s
    const int b = pair >> 6, rs = pair & 63, r = rs >> 3, s = rs & 7;
    const float4* kr = (const float4*)(Kf + (size_t)b * 32768 + (size_t)r * 4096);
    const float4* jsv = (const float4*)(Jf + (size_t)b * 32768 + (size_t)s * 4096);
    const int t = threadIdx.x;
    float acc = 0.f;
    #pragma unroll
    for (int k = 0; k < 4; ++k) {
        float4 a = kr[t + k * 256], c = jsv[t + k * 256];
        acc += a.x * c.x + a.y * c.y + a.z * c.z + a.w * c.w;
    }
    #pragma unroll
    for (int off = 32; off; off >>= 1) acc += __shfl_down(acc, off);
    __shared__ float red[4];
    if ((t & 63) == 0) red[t >> 6] = acc;
    __syncthreads();
    if (t == 0) M[pair] = red[0] + red[1] + red[2] + red[3];
}

// ---------------------------------------------------------------------------
// Kernel C: P[b][i][s] = sum_r A[r][i] * M[r][s], A[r][i] = Qf[b][r*4096+i].
// ---------------------------------------------------------------------------
__global__ __launch_bounds__(256) void kC(
    const float* __restrict__ Qf, const float* __restrict__ M,
    float* __restrict__ P)
{
    __shared__ float m_s[64];
    const int t  = threadIdx.x;
    const int b  = blockIdx.x >> 4;
    const int ii = (blockIdx.x & 15) * 256 + t;
    if (t < 64) m_s[t] = M[b * 64 + t];
    __syncthreads();
    float a[8];
    #pragma unroll
    for (int r = 0; r < 8; ++r) a[r] = Qf[(size_t)b * 32768 + (size_t)r * 4096 + ii];
    float p[8];
    #pragma unroll
    for (int s = 0; s < 8; ++s) {
        float acc = 0.f;
        #pragma unroll
        for (int r = 0; r < 8; ++r) acc += a[r] * m_s[r * 8 + s];
        p[s] = acc;
    }
    float* dst = P + ((size_t)b * 4096 + ii) * 8;
    *(float4*)dst       = make_float4(p[0], p[1], p[2], p[3]);
    *((float4*)dst + 1) = make_float4(p[4], p[5], p[6], p[7]);
}

// ---------------------------------------------------------------------------
// Kernel D (hot): out[b][i][c] = gamma * sum_j sigmoid(P_i . Bcol_j) * V[j][c] + x
// Block: 256 threads = 32 rows (il = t>>3) x 8 channel-groups (q = t&7).
// Per chunk of 64 j: stage K rows (8x64) and V (64x32) in LDS;
// phase 1: each thread computes 8 sigmoids (jj = m*8+q) -> s_s[il][jj];
// phase 2: each thread accumulates float4 over 64 jj.
// LDS strides chosen so all access patterns are <=2-way bank aliased (free).
// ---------------------------------------------------------------------------
__global__ __launch_bounds__(256) void kD(
    const float* __restrict__ Pm, const float* __restrict__ Kf,
    const float* __restrict__ Vf, const float* __restrict__ xin,
    const float* __restrict__ gamma, float* __restrict__ out)
{
    const int blk = blockIdx.x;            // 256 blocks = 2 batches * 128 tiles
    const int b   = blk >> 7;
    const int i0  = (blk & 127) * TI;
    const int t   = threadIdx.x;
    const int il  = t >> 3;                // row within tile [0,32)
    const int q   = t & 7;                 // channel group / phase-1 sub-index

    __shared__ float kt_s[8][68];          // K rows r x jj  (stride 68: 2-way max)
    __shared__ float v_s[TJ][36];          // V jj x c       (stride 36)
    __shared__ float s_s[TI][68];          // sigmoid tile   (stride 68, b128-aligned)

    // P row for this thread's il (8 floats)
    const float* prow = Pm + ((size_t)(b * 4096 + i0 + il)) * 8;
    float4 p0 = *(const float4*)prow;
    float4 p1 = *(const float4*)(prow + 4);
    float p[8] = {p0.x, p0.y, p0.z, p0.w, p1.x, p1.y, p1.z, p1.w};

    const float* Kb = Kf + (size_t)b * 32768;
    const float* Vb = Vf + (size_t)b * 131072;

    float4 acc = make_float4(0.f, 0.f, 0.f, 0.f);

    for (int jc = 0; jc < NN / TJ; ++jc) {
        __syncthreads();   // protect LDS from previous phase 2
        // stage K rows: 8 x 64 floats = 128 float4, threads 0..127
        if (t < 128) {
            const int rr = t >> 4, j4 = (t & 15) * 4;
            *(float4*)&kt_s[rr][j4] =
                *(const float4*)(Kb + (size_t)rr * 4096 + jc * TJ + j4);
        }
        // stage V: 64 x 32 floats = 512 float4, 2 per thread
        {
            int f = t, jj = f >> 3, c4 = (f & 7) * 4;
            *(float4*)&v_s[jj][c4] =
                *(const float4*)(Vb + (size_t)(jc * TJ + jj) * 32 + c4);
            f = t + 256; jj = f >> 3; c4 = (f & 7) * 4;
            *(float4*)&v_s[jj][c4] =
                *(const float4*)(Vb + (size_t)(jc * TJ + jj) * 32 + c4);
        }
        __syncthreads();
        // phase 1: sigmoid(P_i . Bcol_j)
        #pragma unroll
        for (int m = 0; m < 8; ++m) {
            const int jj = m * 8 + q;
            float dsum = 0.f;
            #pragma unroll
            for (int r = 0; r < 8; ++r) dsum += p[r] * kt_s[r][jj];
            // sigmoid: exp overflow at very negative dsum gives inf -> rcp -> 0 (correct)
            s_s[il][jj] = __builtin_amdgcn_rcpf(1.0f + __expf(-dsum));
        }
        __syncthreads();
        // phase 2: acc += s * V
        #pragma unroll 4
        for (int j4 = 0; j4 < TJ / 4; ++j4) {
            const float4 s4 = *(const float4*)&s_s[il][j4 * 4];
            const float4 v0 = *(const float4*)&v_s[j4 * 4 + 0][q * 4];
            const float4 v1 = *(const float4*)&v_s[j4 * 4 + 1][q * 4];
            const float4 v2 = *(const float4*)&v_s[j4 * 4 + 2][q * 4];
            const float4 v3 = *(const float4*)&v_s[j4 * 4 + 3][q * 4];
            acc.x += s4.x * v0.x; acc.y += s4.x * v0.y; acc.z += s4.x * v0.z; acc.w += s4.x * v0.w;
            acc.x += s4.y * v1.x; acc.y += s4.y * v1.y; acc.z += s4.y * v1.z; acc.w += s4.y * v1.w;
            acc.x += s4.z * v2.x; acc.y += s4.z * v2.y; acc.z += s4.z * v2.z; acc.w += s4.z * v2.w;
            acc.x += s4.w * v3.x; acc.y += s4.w * v3.y; acc.z += s4.w * v3.z; acc.w += s4.w * v3.w;
        }
    }

    const float g = gamma[0];
    const size_t o = ((size_t)(b * 4096 + i0 + il)) * 32 + q * 4;
    const float4 xv = *(const float4*)(xin + o);
    float4 r4;
    r4.x = g * acc.x + xv.x;
    r4.y = g * acc.y + xv.y;
    r4.z = g * acc.z + xv.z;
    r4.w = g * acc.w + xv.w;
    *(float4*)(out + o) = r4;
}

// ---------------------------------------------------------------------------
extern "C" void kernel_launch(void* const* d_in, const int* in_sizes, int n_in,
                              void* d_out, int out_size, void* d_ws, size_t ws_size,
                              hipStream_t stream)
{
    const float* x     = (const float*)d_in[0];
    const float* gamma = (const float*)d_in[1];
    const float* qw = (const float*)d_in[2];
    const float* qb = (const float*)d_in[3];
    const float* qs = (const float*)d_in[4];
    const float* qo = (const float*)d_in[5];
    const float* kw = (const float*)d_in[6];
    const float* kb = (const float*)d_in[7];
    const float* ks = (const float*)d_in[8];
    const float* ko = (const float*)d_in[9];
    const float* jw = (const float*)d_in[10];
    const float* jb = (const float*)d_in[11];
    const float* js = (const float*)d_in[12];
    const float* jo = (const float*)d_in[13];
    const float* vw = (const float*)d_in[14];
    const float* vb = (const float*)d_in[15];
    const float* vs = (const float*)d_in[16];
    const float* vo = (const float*)d_in[17];

    float* ws = (float*)d_ws;
    float* Qf = ws;                 // 2*4096*8  = 65536
    float* Kf = ws + 65536;         // 65536
    float* Jf = ws + 131072;        // 65536
    float* Vf = ws + 196608;        // 2*4096*32 = 262144
    float* Mm = ws + 458752;        // 2*64      = 128
    float* Pp = ws + 458880;        // 65536  (end: 524416 floats ~= 2.1 MB)

    kA<<<2048, 256, 0, stream>>>(x, qw, qb, qs, qo, kw, kb, ks, ko,
                                 jw, jb, js, jo, vw, vb, vs, vo,
                                 Qf, Kf, Jf, Vf);
    kB<<<128, 256, 0, stream>>>(Kf, Jf, Mm);
    kC<<<32, 256, 0, stream>>>(Qf, Mm, Pp);
    kD<<<256, 256, 0, stream>>>(Pp, Kf, Vf, x, gamma, (float*)d_out);
}

// Round 2
// 145.504 us; speedup vs baseline: 1.6851x; 1.6851x over previous
//
#include <hip/hip_runtime.h>
#include <cstddef>

// Problem constants: (B,W,D,H,C) = (2,16,16,16,32), N = 4096 per batch.
#define NN 4096
#define TJ 64      // j-chunk in kD
#define JSPLIT 8   // j-splits in kD (partial sums reduced by kE)

// ---------------------------------------------------------------------------
// Kernel A: fused Q/K/J/V projections. conv -> +bias -> *scale -> +offset -> relu
// Weights staged in LDS (conv weights at stride 776: 776%32=8 -> the 6
// (conv,co4) groups read 6 distinct 4-bank groups, conflict-free).
// Block = 256 threads = 32 spatial points x 8 groups. grid = 256.
// Phase V: group = c4 (4 channels). Phase QKJ: group g<6 -> (conv, co4).
// ---------------------------------------------------------------------------
__global__ __launch_bounds__(256) void kA(
    const float* __restrict__ x,
    const float* __restrict__ qw, const float* __restrict__ qb,
    const float* __restrict__ qs, const float* __restrict__ qo,
    const float* __restrict__ kw, const float* __restrict__ kb,
    const float* __restrict__ ks, const float* __restrict__ ko,
    const float* __restrict__ jw, const float* __restrict__ jb,
    const float* __restrict__ js, const float* __restrict__ jo,
    const float* __restrict__ vw, const float* __restrict__ vb,
    const float* __restrict__ vs, const float* __restrict__ vo,
    float* __restrict__ Qf, float* __restrict__ Kf,
    float* __restrict__ Jf, float* __restrict__ Vf)
{
    __shared__ float vw_s[1024];        // [ci][co] = ci*32+co
    __shared__ float cw_s[3 * 776];     // conv weights [conv][tap*256+ci*8+co]
    const int t = threadIdx.x;
    for (int i = t; i < 1024; i += 256) vw_s[i] = vw[i];
    for (int i = t; i < 768; i += 256) {
        cw_s[i]        = qw[i];
        cw_s[776 + i]  = kw[i];
        cw_s[1552 + i] = jw[i];
    }
    __syncthreads();

    const int spi = t >> 3;
    const int gsp = blockIdx.x * 32 + spi;      // 0..8191 (b*4096+sp)
    const int b   = gsp >> 12;
    const int sp  = gsp & 4095;
    const int w = sp >> 8, d = (sp >> 4) & 15, h = sp & 15;
    const float4* xr = (const float4*)(x + (size_t)gsp * 32);

    // ---- V (pointwise 32->32): 4 channels per thread ----
    {
        const int c4 = t & 7;
        float4 acc = make_float4(0.f, 0.f, 0.f, 0.f);
        #pragma unroll
        for (int c8 = 0; c8 < 8; ++c8) {
            const float4 xv = xr[c8];
            #pragma unroll
            for (int k = 0; k < 4; ++k) {
                const float xs = (k == 0) ? xv.x : (k == 1) ? xv.y : (k == 2) ? xv.z : xv.w;
                const float4 wv = *(const float4*)&vw_s[(c8 * 4 + k) * 32 + c4 * 4];
                acc.x += xs * wv.x; acc.y += xs * wv.y;
                acc.z += xs * wv.z; acc.w += xs * wv.w;
            }
        }
        const float4 bb = ((const float4*)vb)[c4];
        const float4 sc = ((const float4*)vs)[c4];
        const float4 oo = ((const float4*)vo)[c4];
        float4 r;
        r.x = fmaxf((acc.x + bb.x) * sc.x + oo.x, 0.f);
        r.y = fmaxf((acc.y + bb.y) * sc.y + oo.y, 0.f);
        r.z = fmaxf((acc.z + bb.z) * sc.z + oo.z, 0.f);
        r.w = fmaxf((acc.w + bb.w) * sc.w + oo.w, 0.f);
        ((float4*)(Vf + (size_t)gsp * 32))[c4] = r;
    }

    // ---- Q/K/J (3-tap 1-D convs along d/w/h): groups g<6 active ----
    {
        const int g = t & 7;
        if (g < 6) {
            const int conv = g >> 1;           // 0=Q(d), 1=K(w), 2=J(h)
            const int co4  = g & 1;            // channel half (4 ch)
            const int coord  = (conv == 0) ? d : (conv == 1) ? w : h;
            const int stride = (conv == 0) ? 16 : (conv == 1) ? 256 : 1;
            const float* cw = cw_s + conv * 776;
            float4 acc = make_float4(0.f, 0.f, 0.f, 0.f);
            #pragma unroll
            for (int tap = 0; tap < 3; ++tap) {
                const int cc = coord + tap - 1;
                if (cc < 0 || cc > 15) continue;           // SAME zero-pad
                const float4* xt = (const float4*)(x + (size_t)(gsp + (tap - 1) * stride) * 32);
                #pragma unroll
                for (int c8 = 0; c8 < 8; ++c8) {
                    const float4 xv = xt[c8];
                    #pragma unroll
                    for (int k = 0; k < 4; ++k) {
                        const float xs = (k == 0) ? xv.x : (k == 1) ? xv.y : (k == 2) ? xv.z : xv.w;
                        const float4 wv = *(const float4*)&cw[tap * 256 + (c8 * 4 + k) * 8 + co4 * 4];
                        acc.x += xs * wv.x; acc.y += xs * wv.y;
                        acc.z += xs * wv.z; acc.w += xs * wv.w;
                    }
                }
            }
            const float* bbp = (conv == 0) ? qb : (conv == 1) ? kb : jb;
            const float* scp = (conv == 0) ? qs : (conv == 1) ? ks : js;
            const float* oop = (conv == 0) ? qo : (conv == 1) ? ko : jo;
            const float4 bb = ((const float4*)bbp)[co4];
            const float4 sc = ((const float4*)scp)[co4];
            const float4 oo = ((const float4*)oop)[co4];
            float4 r;
            r.x = fmaxf((acc.x + bb.x) * sc.x + oo.x, 0.f);
            r.y = fmaxf((acc.y + bb.y) * sc.y + oo.y, 0.f);
            r.z = fmaxf((acc.z + bb.z) * sc.z + oo.z, 0.f);
            r.w = fmaxf((acc.w + bb.w) * sc.w + oo.w, 0.f);
            float* dst = (conv == 0) ? Qf : (conv == 1) ? Kf : Jf;
            ((float4*)(dst + (size_t)b * 32768 + (size_t)sp * 8))[co4] = r;
        }
    }
}

// ---------------------------------------------------------------------------
// Kernel B: M[b][r][s] = dot(K_row_r, J_row_s) over N=4096. 128 blocks.
// ---------------------------------------------------------------------------
__global__ __launch_bounds__(256) void kB(
    const float* __restrict__ Kf, const float* __restrict__ Jf,
    float* __restrict__ M)
{
    const int pair = blockIdx.x;           // b*64 + r*8 + s
    const int b = pair >> 6, rs = pair & 63, r = rs >> 3, s = rs & 7;
    const float4* kr = (const float4*)(Kf + (size_t)b * 32768 + (size_t)r * 4096);
    const float4* jv = (const float4*)(Jf + (size_t)b * 32768 + (size_t)s * 4096);
    const int t = threadIdx.x;
    float acc = 0.f;
    #pragma unroll
    for (int k = 0; k < 4; ++k) {
        float4 a = kr[t + k * 256], c = jv[t + k * 256];
        acc += a.x * c.x + a.y * c.y + a.z * c.z + a.w * c.w;
    }
    #pragma unroll
    for (int off = 32; off; off >>= 1) acc += __shfl_down(acc, off);
    __shared__ float red[4];
    if ((t & 63) == 0) red[t >> 6] = acc;
    __syncthreads();
    if (t == 0) M[pair] = red[0] + red[1] + red[2] + red[3];
}

// ---------------------------------------------------------------------------
// Kernel D (hot): partial[js][b][i][c] = sum_{j in split} sigmoid(P_i.Kcol_j)*V[j][c]
// Block: 256 threads, 64 rows (2 per thread: il, il+32), j-split of 512.
// Grid: 2 b x 64 rowtiles x 8 jsplits = 1024 blocks -> 4 blocks/CU.
// P rows computed in-block from Qf and M (kC folded in).
// LDS mappings are all broadcast / <=2-way (free per m136).
// ---------------------------------------------------------------------------
__global__ __launch_bounds__(256) void kD(
    const float* __restrict__ Qf, const float* __restrict__ Mm,
    const float* __restrict__ Kf, const float* __restrict__ Vf,
    float* __restrict__ part)
{
    const int blk = blockIdx.x;
    const int jsp = blk & 7;
    const int rt  = (blk >> 3) & 63;
    const int b   = blk >> 9;
    const int i0  = rt * 64;
    const int j0  = jsp * 512;
    const int t   = threadIdx.x;
    const int il  = t >> 3;            // 0..31
    const int q   = t & 7;             // 4-channel group

    __shared__ float m_s[64];
    __shared__ float kt_s[8][68];      // K rows x jj (stride 68)
    __shared__ float v_s[TJ][36];      // V jj x c (stride 36)
    __shared__ float s_s[64][68];      // sigmoid tile (stride 68, b128-aligned)

    if (t < 64) m_s[t] = Mm[b * 64 + t];
    __syncthreads();

    const float* Kb = Kf + (size_t)b * 32768;
    const float* Vb = Vf + (size_t)b * 131072;

    // P rows for this thread's two rows (kC folded)
    float p0[8], p1[8];
    {
        float a0[8], a1[8];
        #pragma unroll
        for (int r = 0; r < 8; ++r) {
            const float* qr = Qf + (size_t)b * 32768 + (size_t)r * 4096 + i0 + il;
            a0[r] = qr[0];
            a1[r] = qr[32];
        }
        #pragma unroll
        for (int s = 0; s < 8; ++s) {
            float x0 = 0.f, x1 = 0.f;
            #pragma unroll
            for (int r = 0; r < 8; ++r) {
                const float mv = m_s[r * 8 + s];
                x0 += a0[r] * mv;
                x1 += a1[r] * mv;
            }
            p0[s] = x0; p1[s] = x1;
        }
    }

    float4 acc0 = make_float4(0.f, 0.f, 0.f, 0.f);
    float4 acc1 = make_float4(0.f, 0.f, 0.f, 0.f);

    for (int jc = 0; jc < 512 / TJ; ++jc) {
        const int jb = j0 + jc * TJ;
        __syncthreads();               // protect LDS from previous phase 2
        // stage K rows: 8 x 64 = 128 float4 (threads 0..127)
        if (t < 128) {
            const int rr = t >> 4, j4 = (t & 15) * 4;
            *(float4*)&kt_s[rr][j4] = *(const float4*)(Kb + (size_t)rr * 4096 + jb + j4);
        }
        // stage V: 64 x 32 = 512 float4, 2 per thread
        {
            const int c4 = (t & 7) * 4;
            int jj = t >> 3;
            *(float4*)&v_s[jj][c4] = *(const float4*)(Vb + (size_t)(jb + jj) * 32 + c4);
            jj += 32;
            *(float4*)&v_s[jj][c4] = *(const float4*)(Vb + (size_t)(jb + jj) * 32 + c4);
        }
        __syncthreads();
        // phase 1: sigmoids for both rows (K column shared between rows)
        #pragma unroll
        for (int m = 0; m < 8; ++m) {
            const int jj = m * 8 + q;
            float kv[8];
            #pragma unroll
            for (int r = 0; r < 8; ++r) kv[r] = kt_s[r][jj];
            float d0 = 0.f, d1 = 0.f;
            #pragma unroll
            for (int r = 0; r < 8; ++r) { d0 += p0[r] * kv[r]; d1 += p1[r] * kv[r]; }
            s_s[il][jj]      = __builtin_amdgcn_rcpf(1.0f + __expf(-d0));
            s_s[il + 32][jj] = __builtin_amdgcn_rcpf(1.0f + __expf(-d1));
        }
        __syncthreads();
        // phase 2: rank-1 accumulate, 2 rows x 4 channels per thread
        #pragma unroll
        for (int j4 = 0; j4 < TJ / 4; ++j4) {
            const float4 sa = *(const float4*)&s_s[il][j4 * 4];
            const float4 sb = *(const float4*)&s_s[il + 32][j4 * 4];
            #pragma unroll
            for (int k = 0; k < 4; ++k) {
                const float4 vv = *(const float4*)&v_s[j4 * 4 + k][q * 4];
                const float fa = (k == 0) ? sa.x : (k == 1) ? sa.y : (k == 2) ? sa.z : sa.w;
                const float fb = (k == 0) ? sb.x : (k == 1) ? sb.y : (k == 2) ? sb.z : sb.w;
                acc0.x += fa * vv.x; acc0.y += fa * vv.y;
                acc0.z += fa * vv.z; acc0.w += fa * vv.w;
                acc1.x += fb * vv.x; acc1.y += fb * vv.y;
                acc1.z += fb * vv.z; acc1.w += fb * vv.w;
            }
        }
    }

    float* pp = part + (((size_t)jsp * 2 + b) * 4096 + i0 + il) * 32 + q * 4;
    *(float4*)pp = acc0;
    *(float4*)(pp + 1024) = acc1;      // row +32 -> +32*32 floats
}

// ---------------------------------------------------------------------------
// Kernel E: out = gamma * sum_js partial + x   (65536 float4 elements)
// ---------------------------------------------------------------------------
__global__ __launch_bounds__(256) void kE(
    const float* __restrict__ part, const float* __restrict__ xin,
    const float* __restrict__ gamma, float* __restrict__ out)
{
    const int f = blockIdx.x * 256 + threadIdx.x;   // float4 index
    const float4* p4 = (const float4*)part;
    float4 s = p4[f];
    #pragma unroll
    for (int j = 1; j < JSPLIT; ++j) {
        const float4 v = p4[(size_t)j * 65536 + f];
        s.x += v.x; s.y += v.y; s.z += v.z; s.w += v.w;
    }
    const float g = gamma[0];
    const float4 xv = ((const float4*)xin)[f];
    float4 r;
    r.x = g * s.x + xv.x;
    r.y = g * s.y + xv.y;
    r.z = g * s.z + xv.z;
    r.w = g * s.w + xv.w;
    ((float4*)out)[f] = r;
}

// ---------------------------------------------------------------------------
extern "C" void kernel_launch(void* const* d_in, const int* in_sizes, int n_in,
                              void* d_out, int out_size, void* d_ws, size_t ws_size,
                              hipStream_t stream)
{
    const float* x     = (const float*)d_in[0];
    const float* gamma = (const float*)d_in[1];
    const float* qw = (const float*)d_in[2];
    const float* qb = (const float*)d_in[3];
    const float* qs = (const float*)d_in[4];
    const float* qo = (const float*)d_in[5];
    const float* kw = (const float*)d_in[6];
    const float* kb = (const float*)d_in[7];
    const float* ks = (const float*)d_in[8];
    const float* ko = (const float*)d_in[9];
    const float* jw = (const float*)d_in[10];
    const float* jb = (const float*)d_in[11];
    const float* js = (const float*)d_in[12];
    const float* jo = (const float*)d_in[13];
    const float* vw = (const float*)d_in[14];
    const float* vb = (const float*)d_in[15];
    const float* vs = (const float*)d_in[16];
    const float* vo = (const float*)d_in[17];

    float* ws = (float*)d_ws;
    float* Qf = ws;                 // 65536
    float* Kf = ws + 65536;         // 65536
    float* Jf = ws + 131072;        // 65536
    float* Vf = ws + 196608;        // 262144
    float* Mm = ws + 458752;        // 128
    float* Pt = ws + 458880;        // 8 * 262144 = 2097152 (end ~10.2 MB)

    kA<<<256, 256, 0, stream>>>(x, qw, qb, qs, qo, kw, kb, ks, ko,
                                jw, jb, js, jo, vw, vb, vs, vo,
                                Qf, Kf, Jf, Vf);
    kB<<<128, 256, 0, stream>>>(Kf, Jf, Mm);
    kD<<<1024, 256, 0, stream>>>(Qf, Mm, Kf, Vf, Pt);
    kE<<<256, 256, 0, stream>>>(Pt, x, gamma, (float*)d_out);
}

// Round 3
// 127.304 us; speedup vs baseline: 1.9260x; 1.1430x over previous
//
#include <hip/hip_runtime.h>
#include <cstddef>

// Problem constants: (B,W,D,H,C) = (2,16,16,16,32), N = 4096 per batch.
#define NN 4096
#define JSPLIT 8

typedef short bf16x8 __attribute__((ext_vector_type(8)));
typedef float f32x4 __attribute__((ext_vector_type(4)));

__device__ __forceinline__ unsigned short f2bf(float f) {
    union { float f; unsigned u; } v; v.f = f;
    unsigned r = v.u + 0x7fffu + ((v.u >> 16) & 1u);   // RNE
    return (unsigned short)(r >> 16);
}

// ---------------------------------------------------------------------------
// Kernel A: fused Q/K/J/V projections + M = K.J^T (kB folded in via atomics).
// Outputs: Qf,Kf fp32 [b][r*4096+sp]; Vt bf16 [b][c*4096+sp] (transposed, the
// B-operand layout kD's MFMA wants); Mm[b*64 + r*8 + s] accumulated atomically
// (must be pre-zeroed by a hipMemsetAsync before this kernel).
// Block = 256 threads = 32 spatial points x 8 groups, grid = 256.
// ---------------------------------------------------------------------------
__global__ __launch_bounds__(256) void kA(
    const float* __restrict__ x,
    const float* __restrict__ qw, const float* __restrict__ qb,
    const float* __restrict__ qs, const float* __restrict__ qo,
    const float* __restrict__ kw, const float* __restrict__ kb,
    const float* __restrict__ ks, const float* __restrict__ ko,
    const float* __restrict__ jw, const float* __restrict__ jb,
    const float* __restrict__ js, const float* __restrict__ jo,
    const float* __restrict__ vw, const float* __restrict__ vb,
    const float* __restrict__ vs, const float* __restrict__ vo,
    float* __restrict__ Qf, float* __restrict__ Kf,
    unsigned short* __restrict__ Vt, float* __restrict__ Mm)
{
    __shared__ float vw_s[1024];        // [ci][co]
    __shared__ float cw_s[3 * 776];     // conv weights [conv][tap*256+ci*8+co]
    __shared__ float Kl[32][8];         // this block's K octets
    __shared__ float Jl[32][8];         // this block's J octets
    const int t = threadIdx.x;
    for (int i = t; i < 1024; i += 256) vw_s[i] = vw[i];
    for (int i = t; i < 768; i += 256) {
        cw_s[i]        = qw[i];
        cw_s[776 + i]  = kw[i];
        cw_s[1552 + i] = jw[i];
    }
    __syncthreads();

    const int spi = t >> 3;
    const int gsp = blockIdx.x * 32 + spi;      // b*4096+sp (b uniform per block)
    const int b   = gsp >> 12;
    const int sp  = gsp & 4095;
    const int w = sp >> 8, d = (sp >> 4) & 15, h = sp & 15;
    const float4* xr = (const float4*)(x + (size_t)gsp * 32);

    // ---- V (pointwise 32->32): 4 channels per thread, stored bf16 transposed ----
    {
        const int c4 = t & 7;
        float4 acc = make_float4(0.f, 0.f, 0.f, 0.f);
        #pragma unroll
        for (int c8 = 0; c8 < 8; ++c8) {
            const float4 xv = xr[c8];
            #pragma unroll
            for (int k = 0; k < 4; ++k) {
                const float xs = (k == 0) ? xv.x : (k == 1) ? xv.y : (k == 2) ? xv.z : xv.w;
                const float4 wv = *(const float4*)&vw_s[(c8 * 4 + k) * 32 + c4 * 4];
                acc.x += xs * wv.x; acc.y += xs * wv.y;
                acc.z += xs * wv.z; acc.w += xs * wv.w;
            }
        }
        const float4 bb = ((const float4*)vb)[c4];
        const float4 sc = ((const float4*)vs)[c4];
        const float4 oo = ((const float4*)vo)[c4];
        float4 r;
        r.x = fmaxf((acc.x + bb.x) * sc.x + oo.x, 0.f);
        r.y = fmaxf((acc.y + bb.y) * sc.y + oo.y, 0.f);
        r.z = fmaxf((acc.z + bb.z) * sc.z + oo.z, 0.f);
        r.w = fmaxf((acc.w + bb.w) * sc.w + oo.w, 0.f);
        unsigned short* vt = Vt + (size_t)b * 131072 + (size_t)(c4 * 4) * 4096 + sp;
        vt[0]        = f2bf(r.x);
        vt[4096]     = f2bf(r.y);
        vt[2 * 4096] = f2bf(r.z);
        vt[3 * 4096] = f2bf(r.w);
    }

    // ---- Q/K/J (3-tap 1-D convs along d/w/h): groups g<6 active ----
    {
        const int g = t & 7;
        if (g < 6) {
            const int conv = g >> 1;           // 0=Q(d), 1=K(w), 2=J(h)
            const int co4  = g & 1;
            const int coord  = (conv == 0) ? d : (conv == 1) ? w : h;
            const int stride = (conv == 0) ? 16 : (conv == 1) ? 256 : 1;
            const float* cw = cw_s + conv * 776;
            float4 acc = make_float4(0.f, 0.f, 0.f, 0.f);
            #pragma unroll
            for (int tap = 0; tap < 3; ++tap) {
                const int cc = coord + tap - 1;
                if (cc < 0 || cc > 15) continue;           // SAME zero-pad
                const float4* xt = (const float4*)(x + (size_t)(gsp + (tap - 1) * stride) * 32);
                #pragma unroll
                for (int c8 = 0; c8 < 8; ++c8) {
                    const float4 xv = xt[c8];
                    #pragma unroll
                    for (int k = 0; k < 4; ++k) {
                        const float xs = (k == 0) ? xv.x : (k == 1) ? xv.y : (k == 2) ? xv.z : xv.w;
                        const float4 wv = *(const float4*)&cw[tap * 256 + (c8 * 4 + k) * 8 + co4 * 4];
                        acc.x += xs * wv.x; acc.y += xs * wv.y;
                        acc.z += xs * wv.z; acc.w += xs * wv.w;
                    }
                }
            }
            const float* bbp = (conv == 0) ? qb : (conv == 1) ? kb : jb;
            const float* scp = (conv == 0) ? qs : (conv == 1) ? ks : js;
            const float* oop = (conv == 0) ? qo : (conv == 1) ? ko : jo;
            const float4 bb = ((const float4*)bbp)[co4];
            const float4 sc = ((const float4*)scp)[co4];
            const float4 oo = ((const float4*)oop)[co4];
            float4 r;
            r.x = fmaxf((acc.x + bb.x) * sc.x + oo.x, 0.f);
            r.y = fmaxf((acc.y + bb.y) * sc.y + oo.y, 0.f);
            r.z = fmaxf((acc.z + bb.z) * sc.z + oo.z, 0.f);
            r.w = fmaxf((acc.w + bb.w) * sc.w + oo.w, 0.f);
            if (conv == 0) {
                ((float4*)(Qf + (size_t)b * 32768 + (size_t)sp * 8))[co4] = r;
            } else if (conv == 1) {
                ((float4*)(Kf + (size_t)b * 32768 + (size_t)sp * 8))[co4] = r;
                *(float4*)&Kl[spi][co4 * 4] = r;
            } else {
                *(float4*)&Jl[spi][co4 * 4] = r;
            }
        }
    }

    // ---- M partial: outer products of this block's 32 (K,J) octets ----
    __syncthreads();
    if (t < 64) {
        const int r = t >> 3, s = t & 7;
        float acc = 0.f;
        #pragma unroll 8
        for (int i = 0; i < 32; ++i) acc += Kl[i][r] * Jl[i][s];
        atomicAdd(&Mm[b * 64 + t], acc);
    }
}

// ---------------------------------------------------------------------------
// Kernel D: out[b][i][c] += gamma * sum_{j in split} sigmoid(P_i.Kcol_j)*V[j][c]
// (out pre-initialized to x by a D2D copy; kE folded in via atomics.)
// Block: 256 threads = 4 waves, TI=64 rows, j-split of 512 (8 chunks of 64).
// Grid: 2b x 64 rowtiles x 8 jsplits = 1024 blocks.
// Phase 1 (fp32 VALU): sigmoid(P.Kcol) -> LDS bf16 tile in A-frag order.
// Phase 2 (MFMA): mfma_f32_16x16x32_bf16, A from LDS, B direct from global Vt.
//   Verified layouts (m89/m120): A[m=lane&15][k=quad*8+j]; B[k=quad*8+j][n=lane&15];
//   C/D: col=lane&15, row=quad*4+reg.
// ---------------------------------------------------------------------------
__global__ __launch_bounds__(256) void kD(
    const float* __restrict__ Qf, const float* __restrict__ Mm,
    const float* __restrict__ Kf, const unsigned short* __restrict__ Vt,
    const float* __restrict__ gamma, float* __restrict__ out)
{
    const int blk = blockIdx.x;
    const int jsp = blk & 7;
    const int rt  = (blk >> 3) & 63;
    const int b   = blk >> 9;
    const int i0  = rt * 64;
    const int j0  = jsp * 512;
    const int t   = threadIdx.x;
    // phase-1 mapping: 16 rowgroups (4 rows) x 16 jgroups (4 j)
    const int jg = t & 15, rg = t >> 4;
    // phase-2 mapping: wave w covers rows w*16..w*16+15 (== rg w*4..w*4+3)
    const int w = t >> 6, lane = t & 63;
    const int m = lane & 15, quad = lane >> 4;

    __shared__ float m_s[64];
    __shared__ float kt_s[8][68];            // K-chunk fp32 [r][j], conflict-free reads
    __shared__ unsigned short s_lds[64][72]; // sigmoid tile bf16 (stride 72: 16B rows, 2-way max)

    if (t < 64) m_s[t] = Mm[b * 64 + t];
    __syncthreads();

    // P[4 rows][8] = Q-rows . M  (kC folded; recomputed per block, trivial)
    float P[4][8];
    {
        float a[4][8];
        #pragma unroll
        for (int r = 0; r < 8; ++r) {
            const float* qr = Qf + (size_t)b * 32768 + (size_t)r * 4096 + i0 + rg * 4;
            #pragma unroll
            for (int ri = 0; ri < 4; ++ri) a[ri][r] = qr[ri];
        }
        #pragma unroll
        for (int s = 0; s < 8; ++s) {
            #pragma unroll
            for (int ri = 0; ri < 4; ++ri) {
                float acc = 0.f;
                #pragma unroll
                for (int r = 0; r < 8; ++r) acc += a[ri][r] * m_s[r * 8 + s];
                P[ri][s] = acc;
            }
        }
    }

    const float* Kb = Kf + (size_t)b * 32768;
    const unsigned short* Vb = Vt + (size_t)b * 131072;

    f32x4 acc0 = {0.f, 0.f, 0.f, 0.f};
    f32x4 acc1 = {0.f, 0.f, 0.f, 0.f};

    for (int jc = 0; jc < 8; ++jc) {
        const int jb = j0 + jc * 64;
        __syncthreads();                     // prev phase-2 done with s_lds
        if (t < 128) {                       // stage K chunk: 8 x 64 fp32
            const int rr = t >> 4, j4 = (t & 15) * 4;
            *(float4*)&kt_s[rr][j4] = *(const float4*)(Kb + (size_t)rr * 4096 + jb + j4);
        }
        __syncthreads();
        // phase 1: 16 sigmoids per thread (4 rows x 4 j), write bf16 to s_lds
        float sv[4][4];
        #pragma unroll
        for (int jt = 0; jt < 4; ++jt) {
            const int j = jg * 4 + jt;
            float kv[8];
            #pragma unroll
            for (int r = 0; r < 8; ++r) kv[r] = kt_s[r][j];
            #pragma unroll
            for (int ri = 0; ri < 4; ++ri) {
                float dsum = 0.f;
                #pragma unroll
                for (int r = 0; r < 8; ++r) dsum += P[ri][r] * kv[r];
                sv[ri][jt] = __builtin_amdgcn_rcpf(1.0f + __expf(-dsum));
            }
        }
        #pragma unroll
        for (int ri = 0; ri < 4; ++ri) {
            const unsigned p01 = (unsigned)f2bf(sv[ri][0]) | ((unsigned)f2bf(sv[ri][1]) << 16);
            const unsigned p23 = (unsigned)f2bf(sv[ri][2]) | ((unsigned)f2bf(sv[ri][3]) << 16);
            *(uint2*)&s_lds[rg * 4 + ri][jg * 4] = make_uint2(p01, p23);
        }
        __syncthreads();
        // phase 2: 4 MFMAs per wave (2 k-tiles x 2 n-tiles), B direct from global
        #pragma unroll
        for (int kt = 0; kt < 2; ++kt) {
            const bf16x8 af = *(const bf16x8*)&s_lds[w * 16 + m][kt * 32 + quad * 8];
            {
                const bf16x8 bv = *(const bf16x8*)(Vb + (size_t)m * 4096 + jb + kt * 32 + quad * 8);
                acc0 = __builtin_amdgcn_mfma_f32_16x16x32_bf16(af, bv, acc0, 0, 0, 0);
            }
            {
                const bf16x8 bv = *(const bf16x8*)(Vb + (size_t)(16 + m) * 4096 + jb + kt * 32 + quad * 8);
                acc1 = __builtin_amdgcn_mfma_f32_16x16x32_bf16(af, bv, acc1, 0, 0, 0);
            }
        }
    }

    // epilogue: atomic accumulate gamma-scaled partials onto out (pre-set to x)
    const float g = gamma[0];
    #pragma unroll
    for (int reg = 0; reg < 4; ++reg) {
        const int row = i0 + w * 16 + quad * 4 + reg;
        float* op = out + ((size_t)b * 4096 + row) * 32 + m;
        atomicAdd(op,      g * acc0[reg]);
        atomicAdd(op + 16, g * acc1[reg]);
    }
}

// ---------------------------------------------------------------------------
extern "C" void kernel_launch(void* const* d_in, const int* in_sizes, int n_in,
                              void* d_out, int out_size, void* d_ws, size_t ws_size,
                              hipStream_t stream)
{
    const float* x     = (const float*)d_in[0];
    const float* gamma = (const float*)d_in[1];
    const float* qw = (const float*)d_in[2];
    const float* qb = (const float*)d_in[3];
    const float* qs = (const float*)d_in[4];
    const float* qo = (const float*)d_in[5];
    const float* kw = (const float*)d_in[6];
    const float* kb = (const float*)d_in[7];
    const float* ks = (const float*)d_in[8];
    const float* ko = (const float*)d_in[9];
    const float* jw = (const float*)d_in[10];
    const float* jb = (const float*)d_in[11];
    const float* js = (const float*)d_in[12];
    const float* jo = (const float*)d_in[13];
    const float* vw = (const float*)d_in[14];
    const float* vb = (const float*)d_in[15];
    const float* vs = (const float*)d_in[16];
    const float* vo = (const float*)d_in[17];

    float* ws = (float*)d_ws;
    float* Qf = ws;                                   // 65536 floats
    float* Kf = ws + 65536;                           // 65536
    float* Mm = ws + 131072;                          // 128
    unsigned short* Vt = (unsigned short*)(ws + 131200); // 262144 bf16 (16B-aligned)

    hipMemsetAsync(Mm, 0, 128 * sizeof(float), stream);
    hipMemcpyAsync(d_out, x, (size_t)262144 * sizeof(float),
                   hipMemcpyDeviceToDevice, stream);
    kA<<<256, 256, 0, stream>>>(x, qw, qb, qs, qo, kw, kb, ks, ko,
                                jw, jb, js, jo, vw, vb, vs, vo,
                                Qf, Kf, Vt, Mm);
    kD<<<1024, 256, 0, stream>>>(Qf, Mm, Kf, Vt, gamma, (float*)d_out);
}